// Round 2
// baseline (142.847 us; speedup 1.0000x reference)
//
#include <hip/hip_runtime.h>

#define HW  16384
#define WD  128

#define TS   16            // center tile side
#define HS   18            // halo side
#define HP   (HS * HS)     // 324 halo pixels
#define PRS  20            // padded halo row stride (slots)
#define PLS  360           // plane stride per c4 (ushort4 slots) = 18*20

__device__ __forceinline__ unsigned short f2bf(float f) {
    unsigned int u = __builtin_bit_cast(unsigned int, f);
    u += 0x7FFFu + ((u >> 16) & 1u);          // RNE
    return (unsigned short)(u >> 16);
}
__device__ __forceinline__ float bf2f(unsigned int s) {
    return __builtin_bit_cast(float, (s & 0xFFFFu) << 16);
}
__device__ __forceinline__ float ftanh(float v) {
    const float e = __expf(2.0f * v);
    return 1.0f - __fdividef(2.0f, e + 1.0f);
}

// ---- la_pre: pointwise, zero redundancy. Per (px, b, p):
//   t_p = tanh(bn1(conv1_p(x)))          (fp32, never stored)
//   rows 0..9 of conv2_p + bn2 -> nb planes (c<8) / mask planes (c>=8), fp32
//   v_p = Wv_p . x -> bf16, 4 uint4 planes of 8 ch each
__global__ __launch_bounds__(256) void la_pre(
    const float* __restrict__ x,
    const float* __restrict__ w1, const float* __restrict__ b1,
    const float* __restrict__ g1, const float* __restrict__ be1,
    const float* __restrict__ m1, const float* __restrict__ v1,
    const float* __restrict__ w2, const float* __restrict__ b2,
    const float* __restrict__ g2, const float* __restrict__ be2,
    const float* __restrict__ m2, const float* __restrict__ v2,
    const float* __restrict__ wv,
    uint4* __restrict__ v4, float* __restrict__ nb, float* __restrict__ mask)
{
    const int pix = blockIdx.x * blockDim.x + threadIdx.x;   // 0..16383
    const int b   = blockIdx.y;
    const int p   = blockIdx.z;                              // t-group 0..7

    const float* xp = x + (size_t)(b * 256 + p * 32) * HW + pix;
    float xv[32];
#pragma unroll
    for (int c = 0; c < 32; ++c) xv[c] = xp[(size_t)c * HW];

    // conv1 + bn1 + tanh (weights/bn thread-uniform -> scalar loads)
    const float* w1g = w1 + p * 256;
    float tv[8];
#pragma unroll
    for (int o = 0; o < 8; ++o) {
        float a = 0.f;
#pragma unroll
        for (int ci = 0; ci < 32; ++ci) a = fmaf(xv[ci], w1g[o * 32 + ci], a);
        const int ch = p * 8 + o;
        const float inv = g1[ch] * rsqrtf(v1[ch] + 1e-5f);
        const float add = be1[ch] + (b1[ch] - m1[ch]) * inv;
        tv[o] = ftanh(fmaf(a, inv, add));
    }

    // conv2 rows 0..9 of group p + bn2, scatter to nb / mask planes
#pragma unroll
    for (int o = 0; o < 10; ++o) {
        const int c = p * 10 + o;                 // global mn channel
        float a = 0.f;
#pragma unroll
        for (int i = 0; i < 8; ++i) a = fmaf(tv[i], w2[p * 80 + o * 8 + i], a);
        const float inv = g2[c] * rsqrtf(v2[c] + 1e-5f);
        const float add = be2[c] + (b2[c] - m2[c]) * inv;
        const float val = fmaf(a, inv, add);
        if (c < 8) {                              // neighbor plane (p==0 only)
            nb[(size_t)(b * 8 + c) * HW + pix] = val;
        } else {                                  // mask plane [b][g][k]
            const int gk = c - 8, g = gk / 9, k = gk - 9 * g;
            mask[((size_t)(b * 8 + g) * 9 + k) * HW + pix] = val;
        }
    }

    // v = Wv_p . x, bf16-packed: 4 planes of uint4 (8 ch each), coalesced
    const float* wvp = wv + p * 1024;
#pragma unroll
    for (int c8 = 0; c8 < 4; ++c8) {
        float ov[8];
#pragma unroll
        for (int j = 0; j < 8; ++j) {
            float a = 0.f;
#pragma unroll
            for (int ci = 0; ci < 32; ++ci)
                a = fmaf(xv[ci], wvp[(c8 * 8 + j) * 32 + ci], a);
            ov[j] = a;
        }
        uint4 u;
        u.x = (unsigned)f2bf(ov[0]) | ((unsigned)f2bf(ov[1]) << 16);
        u.y = (unsigned)f2bf(ov[2]) | ((unsigned)f2bf(ov[3]) << 16);
        u.z = (unsigned)f2bf(ov[4]) | ((unsigned)f2bf(ov[5]) << 16);
        u.w = (unsigned)f2bf(ov[6]) | ((unsigned)f2bf(ov[7]) << 16);
        v4[((size_t)((b * 8 + p) * 4) + c8) * HW + pix] = u;
    }
}

// ---- la_attn: pure stencil stream. Per center px:
//   lg[k] = mask_k(px) + nb(tap) ; softmax ; out = rs * sum_k e_k v(tap)
__global__ __launch_bounds__(256, 4) void la_attn(
    const uint4* __restrict__ v4, const float* __restrict__ nb,
    const float* __restrict__ mask, float* __restrict__ out)
{
    __shared__ ushort4 vt[8 * PLS];   // v halo, bf16x4 planes: 23040 B
    __shared__ float   nbs[PLS];      // neighbor plane fp32:    1440 B

    const int tid  = threadIdx.x;
    const int bg   = blockIdx.x;
    const int tile = blockIdx.y;               // 0..63
    const int b    = bg >> 3, g = bg & 7;
    const int ty0  = (tile >> 3) * TS;
    const int tx0  = (tile & 7) * TS;

    // center-pixel mask prefetch (independent of LDS -> overlaps halo fill)
    const int cy  = tid >> 4, cx = tid & 15;
    const int iy  = ty0 + cy, ix = tx0 + cx;
    const int pix = iy * WD + ix;
    const float* mp = mask + (size_t)(b * 8 + g) * 9 * HW + pix;
    float mk[9];
#pragma unroll
    for (int k = 0; k < 9; ++k) mk[k] = mp[(size_t)k * HW];

    // ---- phase 1: pure copy halo -> LDS ----
    const uint4* vg  = v4 + (size_t)((b * 8 + g) * 4) * HW;
    const float* nbp = nb + (size_t)(b * 8 + g) * HW;
    for (int hp = tid; hp < HP; hp += 256) {
        const int hy = hp / HS, hx = hp - hy * HS;
        const int hiy = ty0 + hy - 1, hix = tx0 + hx - 1;
        const int slot = hy * PRS + hx;
        if (((unsigned)hiy < 128u) && ((unsigned)hix < 128u)) {
            const int po = hiy * WD + hix;
            nbs[slot] = nbp[po];
#pragma unroll
            for (int c8 = 0; c8 < 4; ++c8) {
                const uint4 u = vg[(size_t)c8 * HW + po];
                vt[(2 * c8 + 0) * PLS + slot] = make_ushort4(
                    (unsigned short)u.x, (unsigned short)(u.x >> 16),
                    (unsigned short)u.y, (unsigned short)(u.y >> 16));
                vt[(2 * c8 + 1) * PLS + slot] = make_ushort4(
                    (unsigned short)u.z, (unsigned short)(u.z >> 16),
                    (unsigned short)u.w, (unsigned short)(u.w >> 16));
            }
        } else {
            const ushort4 z = make_ushort4(0, 0, 0, 0);
#pragma unroll
            for (int c4 = 0; c4 < 8; ++c4) vt[c4 * PLS + slot] = z;
            nbs[slot] = 0.f;       // zero-padded neighbor
        }
    }
    __syncthreads();

    // ---- phase 2: softmax + weighted v sum ----
    float lg[9];
    float mx = -1e30f;
#pragma unroll
    for (int k = 0; k < 9; ++k) {
        lg[k] = mk[k] + nbs[(cy + k / 3) * PRS + (cx + k % 3)];
        mx = fmaxf(mx, lg[k]);
    }
    float ssum = 0.f;
#pragma unroll
    for (int k = 0; k < 9; ++k) { lg[k] = __expf(lg[k] - mx); ssum += lg[k]; }
    const float rs = 1.f / ssum;               // applied once at the store

    float s[32];
#pragma unroll
    for (int c = 0; c < 32; ++c) s[c] = 0.f;
#pragma unroll
    for (int k = 0; k < 9; ++k) {
        const int slot = (cy + k / 3) * PRS + (cx + k % 3);
        const float e = lg[k];
#pragma unroll
        for (int c4 = 0; c4 < 8; ++c4) {
            const ushort4 vv = vt[c4 * PLS + slot];
            s[c4 * 4 + 0] = fmaf(e, bf2f(vv.x), s[c4 * 4 + 0]);
            s[c4 * 4 + 1] = fmaf(e, bf2f(vv.y), s[c4 * 4 + 1]);
            s[c4 * 4 + 2] = fmaf(e, bf2f(vv.z), s[c4 * 4 + 2]);
            s[c4 * 4 + 3] = fmaf(e, bf2f(vv.w), s[c4 * 4 + 3]);
        }
    }

    float* og = out + (size_t)(b * 256 + g * 32) * HW + pix;
#pragma unroll 8
    for (int o = 0; o < 32; ++o)
        __builtin_nontemporal_store(s[o] * rs, og + (size_t)o * HW);
}

extern "C" void kernel_launch(void* const* d_in, const int* in_sizes, int n_in,
                              void* d_out, int out_size, void* d_ws, size_t ws_size,
                              hipStream_t stream)
{
    const float* x   = (const float*)d_in[0];
    const float* w1  = (const float*)d_in[1];
    const float* b1  = (const float*)d_in[2];
    const float* g1  = (const float*)d_in[3];
    const float* be1 = (const float*)d_in[4];
    const float* m1  = (const float*)d_in[5];
    const float* v1  = (const float*)d_in[6];
    const float* w2  = (const float*)d_in[7];
    const float* b2  = (const float*)d_in[8];
    const float* g2  = (const float*)d_in[9];
    const float* be2 = (const float*)d_in[10];
    const float* m2  = (const float*)d_in[11];
    const float* v2  = (const float*)d_in[12];
    const float* wv  = (const float*)d_in[13];

    float* out = (float*)d_out;

    // workspace: v (bf16, 64 uint4-planes, 16.8 MB) | nb (fp32, 1 MB) | mask (fp32, 9.4 MB)
    uint4* v4  = (uint4*)d_ws;
    float* nbw = (float*)((char*)d_ws + (size_t)64 * HW * 16);
    float* msk = nbw + (size_t)16 * HW;

    dim3 blk(256);
    dim3 gpre(HW / 256, 2, 8);     // 1024 blocks: px x b x t-group
    dim3 gatt(16, 64);             // (bg, tile)

    hipLaunchKernelGGL(la_pre, gpre, blk, 0, stream,
                       x, w1, b1, g1, be1, m1, v1, w2, b2, g2, be2, m2, v2,
                       wv, v4, nbw, msk);
    hipLaunchKernelGGL(la_attn, gatt, blk, 0, stream,
                       v4, nbw, msk, out);
}

// Round 3
// 140.568 us; speedup vs baseline: 1.0162x; 1.0162x over previous
//
#include <hip/hip_runtime.h>

#define HW  16384
#define WD  128

__device__ __forceinline__ unsigned short f2bf(float f) {
    unsigned int u = __builtin_bit_cast(unsigned int, f);
    u += 0x7FFFu + ((u >> 16) & 1u);          // RNE
    return (unsigned short)(u >> 16);
}
__device__ __forceinline__ float bf2f(unsigned int s) {
    return __builtin_bit_cast(float, (s & 0xFFFFu) << 16);
}
__device__ __forceinline__ float ftanh(float v) {
    const float e = __expf(2.0f * v);
    return 1.0f - __fdividef(2.0f, e + 1.0f);
}

// ---- la_pre: pointwise, zero redundancy. Per (px, b, p):
//   t_p = tanh(bn1(conv1_p(x)))          (fp32, never stored)
//   rows 0..9 of conv2_p + bn2 -> nb planes (c<8) / mask planes (c>=8), fp32
//   v_p = Wv_p . x -> bf16, 4 uint4 planes of 8 ch each
__global__ __launch_bounds__(256) void la_pre(
    const float* __restrict__ x,
    const float* __restrict__ w1, const float* __restrict__ b1,
    const float* __restrict__ g1, const float* __restrict__ be1,
    const float* __restrict__ m1, const float* __restrict__ v1,
    const float* __restrict__ w2, const float* __restrict__ b2,
    const float* __restrict__ g2, const float* __restrict__ be2,
    const float* __restrict__ m2, const float* __restrict__ v2,
    const float* __restrict__ wv,
    uint4* __restrict__ v4, float* __restrict__ nb, float* __restrict__ mask)
{
    const int pix = blockIdx.x * blockDim.x + threadIdx.x;   // 0..16383
    const int b   = blockIdx.y;
    const int p   = blockIdx.z;                              // t-group 0..7

    const float* xp = x + (size_t)(b * 256 + p * 32) * HW + pix;
    float xv[32];
#pragma unroll
    for (int c = 0; c < 32; ++c) xv[c] = xp[(size_t)c * HW];

    // conv1 + bn1 + tanh (weights/bn thread-uniform -> scalar loads)
    const float* w1g = w1 + p * 256;
    float tv[8];
#pragma unroll
    for (int o = 0; o < 8; ++o) {
        float a = 0.f;
#pragma unroll
        for (int ci = 0; ci < 32; ++ci) a = fmaf(xv[ci], w1g[o * 32 + ci], a);
        const int ch = p * 8 + o;
        const float inv = g1[ch] * rsqrtf(v1[ch] + 1e-5f);
        const float add = be1[ch] + (b1[ch] - m1[ch]) * inv;
        tv[o] = ftanh(fmaf(a, inv, add));
    }

    // conv2 rows 0..9 of group p + bn2, scatter to nb / mask planes
#pragma unroll
    for (int o = 0; o < 10; ++o) {
        const int c = p * 10 + o;                 // global mn channel
        float a = 0.f;
#pragma unroll
        for (int i = 0; i < 8; ++i) a = fmaf(tv[i], w2[p * 80 + o * 8 + i], a);
        const float inv = g2[c] * rsqrtf(v2[c] + 1e-5f);
        const float add = be2[c] + (b2[c] - m2[c]) * inv;
        const float val = fmaf(a, inv, add);
        if (c < 8) {                              // neighbor plane (p==0 only)
            nb[(size_t)(b * 8 + c) * HW + pix] = val;
        } else {                                  // mask plane [b][g][k]
            const int gk = c - 8, g = gk / 9, k = gk - 9 * g;
            mask[((size_t)(b * 8 + g) * 9 + k) * HW + pix] = val;
        }
    }

    // v = Wv_p . x, bf16-packed: 4 planes of uint4 (8 ch each), coalesced
    const float* wvp = wv + p * 1024;
#pragma unroll
    for (int c8 = 0; c8 < 4; ++c8) {
        float ov[8];
#pragma unroll
        for (int j = 0; j < 8; ++j) {
            float a = 0.f;
#pragma unroll
            for (int ci = 0; ci < 32; ++ci)
                a = fmaf(xv[ci], wvp[(c8 * 8 + j) * 32 + ci], a);
            ov[j] = a;
        }
        uint4 u;
        u.x = (unsigned)f2bf(ov[0]) | ((unsigned)f2bf(ov[1]) << 16);
        u.y = (unsigned)f2bf(ov[2]) | ((unsigned)f2bf(ov[3]) << 16);
        u.z = (unsigned)f2bf(ov[4]) | ((unsigned)f2bf(ov[5]) << 16);
        u.w = (unsigned)f2bf(ov[6]) | ((unsigned)f2bf(ov[7]) << 16);
        v4[((size_t)((b * 8 + p) * 4) + c8) * HW + pix] = u;
    }
}

// ---- la_attn: LDS-free streaming stencil. One thread per output pixel.
//   256 consecutive px per block -> full-cache-line reads/writes on every
//   plane; 3x3 taps hit L1 (8/9 of tap bytes are line re-reads).
__global__ __launch_bounds__(256) void la_attn(
    const uint4* __restrict__ v4, const float* __restrict__ nb,
    const float* __restrict__ mask, float* __restrict__ out)
{
    const int pix = blockIdx.x * blockDim.x + threadIdx.x;   // 0..16383
    const int bg  = blockIdx.y;                              // 0..15
    const int b   = bg >> 3, g = bg & 7;
    const int iy  = pix >> 7, ix = pix & 127;

    const float* mp  = mask + ((size_t)(b * 8 + g) * 9) * HW + pix;
    const float* nbp = nb   + (size_t)(b * 8 + g) * HW + pix;
    const uint4* vg  = v4   + ((size_t)(b * 8 + g) * 4) * HW + pix;

    // logits: mask at center + neighbor plane tap (zero-padded OOB)
    float lg[9];
    float mx = -1e30f;
#pragma unroll
    for (int k = 0; k < 9; ++k) {
        const int dy = k / 3 - 1, dx = k % 3 - 1;
        const bool ok = ((unsigned)(iy + dy) < 128u) && ((unsigned)(ix + dx) < 128u);
        const float nv = ok ? nbp[dy * WD + dx] : 0.f;
        lg[k] = mp[(size_t)k * HW] + nv;
        mx = fmaxf(mx, lg[k]);
    }
    float ssum = 0.f;
#pragma unroll
    for (int k = 0; k < 9; ++k) { lg[k] = __expf(lg[k] - mx); ssum += lg[k]; }
    const float rs = 1.f / ssum;               // applied once at the store

    // s = sum_k e_k * v_tap  (OOB taps contribute zero; exp stays in denom)
    float s[32];
#pragma unroll
    for (int c = 0; c < 32; ++c) s[c] = 0.f;
#pragma unroll
    for (int k = 0; k < 9; ++k) {
        const int dy = k / 3 - 1, dx = k % 3 - 1;
        const bool ok = ((unsigned)(iy + dy) < 128u) && ((unsigned)(ix + dx) < 128u);
        if (ok) {                                 // divergent only in edge waves
            const int off = dy * WD + dx;
            const float e = lg[k];
#pragma unroll
            for (int c8 = 0; c8 < 4; ++c8) {
                const uint4 u = vg[(size_t)c8 * HW + off];
                s[c8 * 8 + 0] = fmaf(e, bf2f(u.x),       s[c8 * 8 + 0]);
                s[c8 * 8 + 1] = fmaf(e, bf2f(u.x >> 16), s[c8 * 8 + 1]);
                s[c8 * 8 + 2] = fmaf(e, bf2f(u.y),       s[c8 * 8 + 2]);
                s[c8 * 8 + 3] = fmaf(e, bf2f(u.y >> 16), s[c8 * 8 + 3]);
                s[c8 * 8 + 4] = fmaf(e, bf2f(u.z),       s[c8 * 8 + 4]);
                s[c8 * 8 + 5] = fmaf(e, bf2f(u.z >> 16), s[c8 * 8 + 5]);
                s[c8 * 8 + 6] = fmaf(e, bf2f(u.w),       s[c8 * 8 + 6]);
                s[c8 * 8 + 7] = fmaf(e, bf2f(u.w >> 16), s[c8 * 8 + 7]);
            }
        }
    }

    float* og = out + (size_t)(b * 256 + g * 32) * HW + pix;
#pragma unroll 8
    for (int o = 0; o < 32; ++o)
        __builtin_nontemporal_store(s[o] * rs, og + (size_t)o * HW);
}

extern "C" void kernel_launch(void* const* d_in, const int* in_sizes, int n_in,
                              void* d_out, int out_size, void* d_ws, size_t ws_size,
                              hipStream_t stream)
{
    const float* x   = (const float*)d_in[0];
    const float* w1  = (const float*)d_in[1];
    const float* b1  = (const float*)d_in[2];
    const float* g1  = (const float*)d_in[3];
    const float* be1 = (const float*)d_in[4];
    const float* m1  = (const float*)d_in[5];
    const float* v1  = (const float*)d_in[6];
    const float* w2  = (const float*)d_in[7];
    const float* b2  = (const float*)d_in[8];
    const float* g2  = (const float*)d_in[9];
    const float* be2 = (const float*)d_in[10];
    const float* m2  = (const float*)d_in[11];
    const float* v2  = (const float*)d_in[12];
    const float* wv  = (const float*)d_in[13];

    float* out = (float*)d_out;

    // workspace: v (bf16, 64 uint4-planes, 16.8 MB) | nb (fp32, 1 MB) | mask (fp32, 9.4 MB)
    uint4* v4  = (uint4*)d_ws;
    float* nbw = (float*)((char*)d_ws + (size_t)64 * HW * 16);
    float* msk = nbw + (size_t)16 * HW;

    dim3 blk(256);
    dim3 gpre(HW / 256, 2, 8);     // 1024 blocks: px x b x t-group
    dim3 gatt(HW / 256, 16);       // 1024 blocks: px x (b,g)

    hipLaunchKernelGGL(la_pre, gpre, blk, 0, stream,
                       x, w1, b1, g1, be1, m1, v1, w2, b2, g2, be2, m2, v2,
                       wv, v4, nbw, msk);
    hipLaunchKernelGGL(la_attn, gatt, blk, 0, stream,
                       v4, nbw, msk, out);
}